// Round 4
// baseline (54.522 us; speedup 1.0000x reference)
//
#include <hip/hip_runtime.h>

#define D_IN  128
#define D_MID 256
#define D_OUT 16
#define NB    512
#define NN    8192
#define NROWS (NB + NN)   // 8704
#define RPB   8           // rows per MLP block -> 1088 blocks
#define BT    8           // query rows per KDE block
#define NSLICE 4          // n-slices for KDE
#define SLICE_N (NN / NSLICE)   // 2048

// ws layout (floats), all 16B-aligned offsets:
//   zq[NB*16] | tarr[NN*16] | aneg[NN*16] | partial[2*NSLICE*NB*16] | W1T[32768] | W2T[1024]
#define ZQ_OFF    0
#define TARR_OFF  (NB * D_OUT)                    // 8192
#define ANEG_OFF  (TARR_OFF + NN * D_OUT)         // 139264
#define PART_OFF  (ANEG_OFF + NN * D_OUT)         // 270336
#define W1T_OFF   (PART_OFF + 2 * NSLICE * NB * D_OUT)  // +65536 = 335872
#define W2T_OFF   (W1T_OFF + D_MID * D_IN)        // 368640

// ---------------- Kernel 0: transpose W1, W2 to coalesced layouts ----------------
__global__ __launch_bounds__(256) void transpose_kernel(
    const float* __restrict__ W1, const float* __restrict__ W2,
    float* __restrict__ W1T, float* __restrict__ W2T)
{
    const int tid = blockIdx.x * 256 + threadIdx.x;
    if (tid < 8192) {
        const int k4 = tid >> 8;            // 0..31
        const int j  = tid & 255;           // 0..255
        const float4 v = reinterpret_cast<const float4*>(W1)[(size_t)j * 32 + k4];
        reinterpret_cast<float4*>(W1T)[(size_t)k4 * 256 + j] = v;
    } else {
        const int t2 = tid - 8192;          // 0..1023
        const int j4 = t2 >> 4;             // 0..63
        const int d  = t2 & 15;             // 0..15
        const float4 v = reinterpret_cast<const float4*>(W2)[(size_t)d * 64 + j4];
        reinterpret_cast<float4*>(W2T)[(size_t)j4 * 16 + d] = v;
    }
}

// ---------------- Kernel 1: per-row MLP + scaled-embedding epilogue ----------------
// zs = s*(relu(row@W1^T)@W2^T), s = sqrt(log2(e)/2)/h.
// queries (row<NB): zq = zs.  refs: tarr = 2*zs, aneg = -zs^2.
__global__ __launch_bounds__(256) void mlp_kernel(
    const float* __restrict__ x, const float* __restrict__ calc_X,
    const float* __restrict__ W1T, const float* __restrict__ W2T,
    const float* __restrict__ hptr,
    float* __restrict__ zq, float* __restrict__ tarr, float* __restrict__ aneg)
{
    __shared__ float rows[RPB][132];
    __shared__ float hid[RPB][260];

    const int t = threadIdx.x;
    const int row0 = blockIdx.x * RPB;

    // ---- stage 8 rows (256 float4, 1 per thread, coalesced) ----
    {
        const int r  = t >> 5;
        const int k4 = t & 31;
        const int grow = row0 + r;
        const float* src = (grow < NB) ? (x + (size_t)grow * D_IN)
                                       : (calc_X + (size_t)(grow - NB) * D_IN);
        const float4 v = reinterpret_cast<const float4*>(src)[k4];
        *reinterpret_cast<float4*>(&rows[r][k4 * 4]) = v;
    }
    __syncthreads();

    const int jj = t & 63;      // lane-consecutive hidden col
    const int rg = t >> 6;      // wave id -> row pair (wave-uniform)

    // ---- phase 1: 2 rows x 4 col-slices register tile, 32 fma / 6 loads per k4 ----
    {
        float acc[2][4] = {};
        const float4* __restrict__ w1t4 = reinterpret_cast<const float4*>(W1T);
#pragma unroll 2
        for (int k4 = 0; k4 < 32; ++k4) {
            float4 wv[4], av[2];
#pragma unroll
            for (int s = 0; s < 4; ++s)
                wv[s] = w1t4[k4 * 256 + s * 64 + jj];            // 1KB/wave, coalesced
#pragma unroll
            for (int q = 0; q < 2; ++q)
                av[q] = *reinterpret_cast<const float4*>(&rows[rg * 2 + q][k4 * 4]); // bcast
#pragma unroll
            for (int q = 0; q < 2; ++q)
#pragma unroll
                for (int s = 0; s < 4; ++s)
                    acc[q][s] = fmaf(av[q].x, wv[s].x, fmaf(av[q].y, wv[s].y,
                                fmaf(av[q].z, wv[s].z, fmaf(av[q].w, wv[s].w, acc[q][s]))));
        }
#pragma unroll
        for (int q = 0; q < 2; ++q)
#pragma unroll
            for (int s = 0; s < 4; ++s)
                hid[rg * 2 + q][s * 64 + jj] = fmaxf(acc[q][s], 0.f);
    }
    __syncthreads();

    // ---- phase 2: thread (r,d,half) half-k dot, shfl combine, scaled epilogue ----
    {
        const int r    = t >> 5;          // 0..7
        const int d    = t & 15;
        const int half = (t >> 4) & 1;
        const float4* __restrict__ w2t4 = reinterpret_cast<const float4*>(W2T);
        float acc = 0.f;
#pragma unroll 4
        for (int k4 = 0; k4 < 32; ++k4) {
            const int j4 = half * 32 + k4;
            const float4 wv = w2t4[j4 * 16 + d];
            const float4 hv = *reinterpret_cast<const float4*>(&hid[r][j4 * 4]);
            acc = fmaf(hv.x, wv.x, fmaf(hv.y, wv.y, fmaf(hv.z, wv.z, fmaf(hv.w, wv.w, acc))));
        }
        acc += __shfl_xor(acc, 16, 64);
        if (half == 0) {
            const float s  = 0.84932180028801904272f / hptr[0];  // sqrt(log2(e)/2)/h
            const float zs = acc * s;
            const int grow = row0 + r;
            if (grow < NB) {
                zq[(size_t)grow * D_OUT + d] = zs;
            } else {
                const size_t k = (size_t)(grow - NB) * D_OUT + d;
                tarr[k] = zs + zs;
                aneg[k] = -zs * zs;
            }
        }
    }
}

// ---------------- Kernel 2: partial KDE sums, u = exp2(t*z + a) ----------------
// grid (NB/BT, NSLICE), 512 threads. Common 2^(-z^2) factor cancels in the ratio.
#define GAUSS(tc, ac, yc, zc, num, den) { \
    const float e_ = fmaf((tc), (zc), (ac)); \
    const float u_ = __builtin_amdgcn_exp2f(e_); \
    (den) += u_; (num) = fmaf(u_, (yc), (num)); }

__global__ __launch_bounds__(512) void kde_kernel(
    const float* __restrict__ zq, const float* __restrict__ tarr,
    const float* __restrict__ aneg, const float* __restrict__ Y,
    float* __restrict__ partial)
{
    __shared__ float red[8][4][64];

    const int t     = threadIdx.x;
    const int b0    = blockIdx.x * BT;
    const int slice = blockIdx.y;

    const int dg    = t & 3;     // float4 group within the 16 dims
    const int chunk = t >> 2;    // 0..127

    float4 z[BT], num[BT], den[BT];
#pragma unroll
    for (int bt = 0; bt < BT; ++bt) {
        z[bt] = reinterpret_cast<const float4*>(zq + (size_t)(b0 + bt) * D_OUT)[dg];
        num[bt] = make_float4(0.f, 0.f, 0.f, 0.f);
        den[bt] = make_float4(0.f, 0.f, 0.f, 0.f);
    }

#pragma unroll 2
    for (int i = 0; i < SLICE_N / 128; ++i) {      // 16 iterations
        const int n = slice * SLICE_N + chunk + 128 * i;
        const float4 tv = reinterpret_cast<const float4*>(tarr)[(size_t)n * 4 + dg];
        const float4 av = reinterpret_cast<const float4*>(aneg)[(size_t)n * 4 + dg];
        const float4 yv = reinterpret_cast<const float4*>(Y)[(size_t)n * 4 + dg];
#pragma unroll
        for (int bt = 0; bt < BT; ++bt) {
            GAUSS(tv.x, av.x, yv.x, z[bt].x, num[bt].x, den[bt].x);
            GAUSS(tv.y, av.y, yv.y, z[bt].y, num[bt].y, den[bt].y);
            GAUSS(tv.z, av.z, yv.z, z[bt].z, num[bt].z, den[bt].z);
            GAUSS(tv.w, av.w, yv.w, z[bt].w, num[bt].w, den[bt].w);
        }
    }

    // ---- butterfly over chunk bits within wave (lanes sharing dg) ----
    float vals[64];
#pragma unroll
    for (int bt = 0; bt < BT; ++bt) {
        vals[bt * 4 + 0] = num[bt].x; vals[bt * 4 + 1] = num[bt].y;
        vals[bt * 4 + 2] = num[bt].z; vals[bt * 4 + 3] = num[bt].w;
        vals[32 + bt * 4 + 0] = den[bt].x; vals[32 + bt * 4 + 1] = den[bt].y;
        vals[32 + bt * 4 + 2] = den[bt].z; vals[32 + bt * 4 + 3] = den[bt].w;
    }
#pragma unroll
    for (int m = 4; m <= 32; m <<= 1) {
#pragma unroll
        for (int v = 0; v < 64; ++v)
            vals[v] += __shfl_xor(vals[v], m, 64);
    }

    const int wave = t >> 6;     // 0..7
    const int lane = t & 63;
    if (lane < 4) {
#pragma unroll
        for (int v = 0; v < 64; ++v) red[wave][lane][v] = vals[v];
    }
    __syncthreads();

    if (t < 128) {
        const int b = t >> 4;        // 0..7
        const int d = t & 15;
        float nsum = 0.f, dsum = 0.f;
#pragma unroll
        for (int w = 0; w < 8; ++w) {
            nsum += red[w][d >> 2][b * 4 + (d & 3)];
            dsum += red[w][d >> 2][32 + b * 4 + (d & 3)];
        }
        const size_t idx = (size_t)slice * NB * D_OUT + (size_t)(b0 + b) * D_OUT + d;
        partial[idx] = nsum;
        partial[(size_t)NSLICE * NB * D_OUT + idx] = dsum;
    }
}

// ---------------- Kernel 3: combine slices + divide ----------------
__global__ __launch_bounds__(256) void combine_kernel(
    const float* __restrict__ partial, float* __restrict__ out)
{
    const int i = blockIdx.x * 256 + threadIdx.x;   // 0..8191
    float nsum = 0.f, dsum = 0.f;
#pragma unroll
    for (int s = 0; s < NSLICE; ++s) {
        nsum += partial[(size_t)s * NB * D_OUT + i];
        dsum += partial[(size_t)(NSLICE + s) * NB * D_OUT + i];
    }
    out[i] = nsum / dsum;
}

extern "C" void kernel_launch(void* const* d_in, const int* in_sizes, int n_in,
                              void* d_out, int out_size, void* d_ws, size_t ws_size,
                              hipStream_t stream) {
    const float* x      = (const float*)d_in[0];
    const float* calc_X = (const float*)d_in[1];
    const float* calc_Y = (const float*)d_in[2];
    const float* W1     = (const float*)d_in[3];
    const float* W2     = (const float*)d_in[4];
    const float* h      = (const float*)d_in[5];

    float* ws      = (float*)d_ws;
    float* zq      = ws + ZQ_OFF;
    float* tarr    = ws + TARR_OFF;
    float* aneg    = ws + ANEG_OFF;
    float* partial = ws + PART_OFF;
    float* W1T     = ws + W1T_OFF;
    float* W2T     = ws + W2T_OFF;
    float* out     = (float*)d_out;

    transpose_kernel<<<dim3(36), dim3(256), 0, stream>>>(W1, W2, W1T, W2T);
    mlp_kernel<<<dim3(NROWS / RPB), dim3(256), 0, stream>>>(x, calc_X, W1T, W2T, h,
                                                            zq, tarr, aneg);
    kde_kernel<<<dim3(NB / BT, NSLICE), dim3(512), 0, stream>>>(zq, tarr, aneg, calc_Y, partial);
    combine_kernel<<<dim3(NB * D_OUT / 256), dim3(256), 0, stream>>>(partial, out);
}